// Round 9
// baseline (133.384 us; speedup 1.0000x reference)
//
#include <hip/hip_runtime.h>

#define B_ 128
#define NPG 512
#define EPG 2048
#define NREL 114
#define XS 18   // row stride (floats) for s_x/s_z: 72B, 8B-aligned float2 rows

// monotone float->uint key (total order matching float compare, no NaNs here)
__device__ __forceinline__ unsigned fkey(float f){
  unsigned u = __float_as_uint(f);
  return (u & 0x80000000u) ? ~u : (u | 0x80000000u);
}
__device__ __forceinline__ float fdec(unsigned k){
  return (k & 0x80000000u) ? __uint_as_float(k & 0x7FFFFFFFu) : __uint_as_float(~k);
}
__device__ __forceinline__ float dot4f(float4 a, float4 b){
  return a.x*b.x + a.y*b.y + a.z*b.z + a.w*b.w;
}

// block-wide: exclusive scan of s_hist[0..512) -> s_off[1..512] inclusive ends,
// s_off[0]=0, s_hist[bin] = exclusive start (running scatter counter).
// Contains 2 internal barriers; caller must barrier after.
__device__ __forceinline__ void scan512(int* s_hist, int* s_off, int* s_wt, int tid){
  int lane = tid & 63, wv = tid >> 6;
  int cnt = 0, inc = 0;
  if (wv < 8){
    cnt = s_hist[wv*64 + lane];
    inc = cnt;
    #pragma unroll
    for (int o=1; o<64; o<<=1){ int t=__shfl_up(inc,o); if (lane>=o) inc += t; }
    if (lane==63) s_wt[wv] = inc;
  }
  __syncthreads();
  if (tid < 8){
    int e = 0;
    #pragma unroll
    for (int j=0;j<8;j++) if (j<tid) e += s_wt[j];
    s_wt[8+tid] = e;
  }
  __syncthreads();
  if (wv < 8){
    int base = s_wt[8+wv];
    s_off[wv*64+lane+1] = base + inc;
    s_hist[wv*64+lane]  = base + inc - cnt;
  }
  if (tid==0) s_off[0] = 0;
}

// One block per graph, LDS-resident, 1 launch. CSR-by-dst; per-node register
// RGAT with 4-lane groups; WORK-STEALING over degree-descending nodes (LPT) --
// balanced waves; two stolen nodes interleaved for 2x ILP on all chains.
__global__ __launch_bounds__(1024) void k_fused(
    const float* __restrict__ emb, const float* __restrict__ gnn_w,
    const float* __restrict__ gnn_q, const float* __restrict__ gnn_k,
    const float* __restrict__ gnn_b, const float* __restrict__ pool_w,
    const float* __restrict__ w1, const float* __restrict__ b1,
    const float* __restrict__ w2, const float* __restrict__ b2,
    const float* __restrict__ w3, const float* __restrict__ b3,
    const int* __restrict__ xattr, const int* __restrict__ src,
    const int* __restrict__ dst, const int* __restrict__ et,
    float* __restrict__ out)
{
  __shared__ float s_x[NPG*XS];            // 36864 B
  __shared__ float s_z[NPG*XS];            // 36864 B (layer output staging)
  __shared__ float s_wq3[3*NREL*XS];       // 24624 B  (all 3 layers hoisted)
  __shared__ float s_wk3[3*NREL*XS];       // 24624 B
  __shared__ float s_logit[EPG];           // 8192 B
  __shared__ unsigned short s_epk[EPG];    // src | (type<<9)
  __shared__ unsigned short s_edst[EPG];   // dst (compaction only)
  __shared__ int s_off[NPG+1];
  __shared__ int s_hist[NPG];
  __shared__ unsigned s_keys[NPG];
  __shared__ int s_mask[NPG];
  __shared__ unsigned short s_perm[NPG];   // degree-DESCENDING order
  __shared__ int s_dh[64];
  __shared__ int s_wt[16];
  __shared__ float s_sum[16];
  __shared__ unsigned s_max16[16];
  __shared__ int s_w[16];
  __shared__ float s_feats[96];
  __shared__ float s_h1[16], s_h2[4];
  __shared__ int s_ctr;

  const int b = blockIdx.x, tid = threadIdx.x;
  const int lane = tid & 63, wv = tid >> 6;
  const int og = tid & 3;                 // lane within 4-lane node group
  const int nb = b*NPG;
  const size_t gb = (size_t)b*EPG;

  // ---- init: emb gather, hist count, Wq/Wk for ALL layers, CSR, perm
  if (tid < NPG){
    int a = xattr[nb + tid];
    const float2* e2 = (const float2*)(emb + a*16);
    #pragma unroll
    for (int c=0;c<8;c++) *(float2*)&s_x[tid*XS + 2*c] = e2[c];
    s_mask[tid] = 1;
  }
  for (int i=tid;i<NPG;i+=1024) s_hist[i]=0;
  if (tid<64) s_dh[tid]=0;
  __syncthreads();
  for (int e=tid;e<EPG;e+=1024) atomicAdd(&s_hist[dst[gb+e]-nb], 1);
  // Wq/Wk: item i = l*1824 + r*16 + d; W row at gnn_w + i*16
  for (int i=tid; i<3*NREL*16; i+=1024){
    int l = i / (NREL*16);
    int rd = i - l*(NREL*16);
    const float4* wr = (const float4*)(gnn_w + (size_t)i*16);
    float4 a0=wr[0],a1=wr[1],a2=wr[2],a3=wr[3];
    const float4* q4 = (const float4*)(gnn_q + l*16);
    const float4* k4 = (const float4*)(gnn_k + l*16);
    int idx = l*(NREL*XS) + (rd>>4)*XS + (rd&15);
    s_wq3[idx] = dot4f(a0,q4[0])+dot4f(a1,q4[1])+dot4f(a2,q4[2])+dot4f(a3,q4[3]);
    s_wk3[idx] = dot4f(a0,k4[0])+dot4f(a1,k4[1])+dot4f(a2,k4[2])+dot4f(a3,k4[3]);
  }
  __syncthreads();
  scan512(s_hist, s_off, s_wt, tid);
  __syncthreads();
  for (int e=tid;e<EPG;e+=1024){
    int d = dst[gb+e]-nb;
    int p = atomicAdd(&s_hist[d], 1);
    s_epk[p]  = (unsigned short)((src[gb+e]-nb) | (et[gb+e]<<9));
    s_edst[p] = (unsigned short)d;
  }
  {
    int mydeg=0, mybin=0;
    if (tid<NPG){
      mydeg = s_off[tid+1]-s_off[tid]; if (mydeg>63) mydeg=63;
      mybin = 63-mydeg;                       // descending degree
      atomicAdd(&s_dh[mybin], 1);
    }
    __syncthreads();
    if (tid<64){
      int c = s_dh[tid], inc = c;
      #pragma unroll
      for (int o=1;o<64;o<<=1){ int t=__shfl_up(inc,o); if (tid>=o) inc+=t; }
      s_dh[tid] = inc - c;
    }
    __syncthreads();
    if (tid<NPG){ int p = atomicAdd(&s_dh[mybin],1); s_perm[p]=(unsigned short)tid; }
  }
  __syncthreads();

  const int cnts[3] = {512, 410, 328};   // static alive counts
  const int kks[2]  = {410, 328};        // ceil(0.8*512), ceil(0.8*410)

  for (int l=0; l<3; ++l){
    if (tid<16){ s_sum[tid]=0.f; s_max16[tid]=0u; }
    if (tid==0) s_ctr = 0;
    __syncthreads();
    // ---- PM: work-stealing, 2 nodes per steal, interleaved edge loops
    {
      const float* wqL = s_wq3 + l*(NREL*XS);
      const float* wkL = s_wk3 + l*(NREL*XS);
      const float* Wl  = gnn_w + (size_t)l*NREL*256;
      float bb4[4], pw4[4]={0,0,0,0}; float rnorm=0.f;
      #pragma unroll
      for (int j=0;j<4;j++) bb4[j] = gnn_b[l*16+4*og+j];
      if (l<2){
        float ss=0.f;
        #pragma unroll
        for (int o=0;o<16;o++){ float p=pool_w[l*16+o]; ss+=p*p; }
        rnorm = rsqrtf(ss);
        #pragma unroll
        for (int j=0;j<4;j++) pw4[j]=pool_w[l*16+4*og+j];
      }
      float ps[4]={0,0,0,0}, pmx[4]={0,0,0,0};   // pool partials (regs)
      for (;;){
        int rk = 0;
        if (og==0) rk = atomicAdd(&s_ctr, 2);
        rk = __shfl(rk, lane & 60);
        if (rk >= NPG) break;
        const int n0 = s_perm[rk], n1 = s_perm[rk+1];
        const int b0 = s_off[n0], d0 = s_off[n0+1]-b0;
        const int b1 = s_off[n1], d1 = s_off[n1+1]-b1;
        const int a0 = s_mask[n0], a1 = s_mask[n1];
        float2 xt00 = *(const float2*)&s_x[n0*XS+4*og];
        float2 xt01 = *(const float2*)&s_x[n0*XS+4*og+2];
        float2 xt10 = *(const float2*)&s_x[n1*XS+4*og];
        float2 xt11 = *(const float2*)&s_x[n1*XS+4*og+2];
        const int dm = d0>d1 ? d0 : d1;
        // pass 1: logits + running max (two independent chains)
        float m0=-1e30f, m1=-1e30f;
        for (int i=0;i<dm;++i){
          if (i<d0){
            int e=b0+i; unsigned pk=s_epk[e]; int s=pk&511, r=pk>>9;
            float2 wq0=*(const float2*)&wqL[r*XS+4*og];
            float2 wq1=*(const float2*)&wqL[r*XS+4*og+2];
            float2 wk0=*(const float2*)&wkL[r*XS+4*og];
            float2 wk1=*(const float2*)&wkL[r*XS+4*og+2];
            float2 xs0=*(const float2*)&s_x[s*XS+4*og];
            float2 xs1=*(const float2*)&s_x[s*XS+4*og+2];
            float a = xt00.x*wq0.x + xt00.y*wq0.y + xt01.x*wq1.x + xt01.y*wq1.y
                    + xs0.x*wk0.x + xs0.y*wk0.y + xs1.x*wk1.x + xs1.y*wk1.y;
            a += __shfl_xor(a,1); a += __shfl_xor(a,2);
            float lg = a>0.f ? a : 0.2f*a;   // leaky_relu 0.2
            if (og==0) s_logit[e]=lg;
            m0 = fmaxf(m0, lg);
          }
          if (i<d1){
            int e=b1+i; unsigned pk=s_epk[e]; int s=pk&511, r=pk>>9;
            float2 wq0=*(const float2*)&wqL[r*XS+4*og];
            float2 wq1=*(const float2*)&wqL[r*XS+4*og+2];
            float2 wk0=*(const float2*)&wkL[r*XS+4*og];
            float2 wk1=*(const float2*)&wkL[r*XS+4*og+2];
            float2 xs0=*(const float2*)&s_x[s*XS+4*og];
            float2 xs1=*(const float2*)&s_x[s*XS+4*og+2];
            float a = xt10.x*wq0.x + xt10.y*wq0.y + xt11.x*wq1.x + xt11.y*wq1.y
                    + xs0.x*wk0.x + xs0.y*wk0.y + xs1.x*wk1.x + xs1.y*wk1.y;
            a += __shfl_xor(a,1); a += __shfl_xor(a,2);
            float lg = a>0.f ? a : 0.2f*a;
            if (og==0) s_logit[e]=lg;
            m1 = fmaxf(m1, lg);
          }
        }
        // pass 2: exp + W-gather aggregation (two streams, 32 loads in flight)
        float den0=0.f, den1=0.f;
        float4 v0 = make_float4(0,0,0,0), v1 = make_float4(0,0,0,0);
        for (int i=0;i<dm;++i){
          if (i<d0){
            int e=b0+i; unsigned pk=s_epk[e]; int s=pk&511, r=pk>>9;
            float ex = __expf(s_logit[e]-m0);
            const float4* wr = (const float4*)(Wl + (size_t)r*256) + og;
            const float* xr = &s_x[s*XS];
            float h0=0,h1=0,h2=0,h3=0;
            #pragma unroll
            for (int d2=0; d2<8; ++d2){
              float2 xs2 = *(const float2*)&xr[2*d2];
              float4 wA = wr[(2*d2)*4], wB = wr[(2*d2+1)*4];
              h0 += xs2.x*wA.x + xs2.y*wB.x;  h1 += xs2.x*wA.y + xs2.y*wB.y;
              h2 += xs2.x*wA.z + xs2.y*wB.z;  h3 += xs2.x*wA.w + xs2.y*wB.w;
            }
            den0 += ex; v0.x += ex*h0; v0.y += ex*h1; v0.z += ex*h2; v0.w += ex*h3;
          }
          if (i<d1){
            int e=b1+i; unsigned pk=s_epk[e]; int s=pk&511, r=pk>>9;
            float ex = __expf(s_logit[e]-m1);
            const float4* wr = (const float4*)(Wl + (size_t)r*256) + og;
            const float* xr = &s_x[s*XS];
            float h0=0,h1=0,h2=0,h3=0;
            #pragma unroll
            for (int d2=0; d2<8; ++d2){
              float2 xs2 = *(const float2*)&xr[2*d2];
              float4 wA = wr[(2*d2)*4], wB = wr[(2*d2+1)*4];
              h0 += xs2.x*wA.x + xs2.y*wB.x;  h1 += xs2.x*wA.y + xs2.y*wB.y;
              h2 += xs2.x*wA.z + xs2.y*wB.z;  h3 += xs2.x*wA.w + xs2.y*wB.w;
            }
            den1 += ex; v1.x += ex*h0; v1.y += ex*h1; v1.z += ex*h2; v1.w += ex*h3;
          }
        }
        // finish both nodes: norm+bias+relu, z-store, pool regs, score key
        {
          float inv = den0>0.f ? 1.f/den0 : 1.f;   // ref: where(den>0, den, 1)
          float z0=v0.x*inv+bb4[0], z1=v0.y*inv+bb4[1],
                z2=v0.z*inv+bb4[2], z3=v0.w*inv+bb4[3];
          z0=z0>0.f?z0:0.f; z1=z1>0.f?z1:0.f; z2=z2>0.f?z2:0.f; z3=z3>0.f?z3:0.f;
          if (!a0){ z0=z1=z2=z3=0.f; }
          *(float2*)&s_z[n0*XS+4*og]   = make_float2(z0,z1);
          *(float2*)&s_z[n0*XS+4*og+2] = make_float2(z2,z3);
          ps[0]+=z0; ps[1]+=z1; ps[2]+=z2; ps[3]+=z3;
          pmx[0]=fmaxf(pmx[0],z0); pmx[1]=fmaxf(pmx[1],z1);
          pmx[2]=fmaxf(pmx[2],z2); pmx[3]=fmaxf(pmx[3],z3);
          if (l<2){
            float dq = z0*pw4[0]+z1*pw4[1]+z2*pw4[2]+z3*pw4[3];
            dq += __shfl_xor(dq,1); dq += __shfl_xor(dq,2);
            if (og==0) s_keys[n0] = a0 ? fkey(tanhf(dq*rnorm)) : 0u;
          }
        }
        {
          float inv = den1>0.f ? 1.f/den1 : 1.f;
          float z0=v1.x*inv+bb4[0], z1=v1.y*inv+bb4[1],
                z2=v1.z*inv+bb4[2], z3=v1.w*inv+bb4[3];
          z0=z0>0.f?z0:0.f; z1=z1>0.f?z1:0.f; z2=z2>0.f?z2:0.f; z3=z3>0.f?z3:0.f;
          if (!a1){ z0=z1=z2=z3=0.f; }
          *(float2*)&s_z[n1*XS+4*og]   = make_float2(z0,z1);
          *(float2*)&s_z[n1*XS+4*og+2] = make_float2(z2,z3);
          ps[0]+=z0; ps[1]+=z1; ps[2]+=z2; ps[3]+=z3;
          pmx[0]=fmaxf(pmx[0],z0); pmx[1]=fmaxf(pmx[1],z1);
          pmx[2]=fmaxf(pmx[2],z2); pmx[3]=fmaxf(pmx[3],z3);
          if (l<2){
            float dq = z0*pw4[0]+z1*pw4[1]+z2*pw4[2]+z3*pw4[3];
            dq += __shfl_xor(dq,1); dq += __shfl_xor(dq,2);
            if (og==0) s_keys[n1] = a1 ? fkey(tanhf(dq*rnorm)) : 0u;
          }
        }
      }
      // pool partials -> LDS once per thread
      #pragma unroll
      for (int j=0;j<4;j++){
        atomicAdd(&s_sum[4*og+j], ps[j]);
        atomicMax(&s_max16[4*og+j], __float_as_uint(pmx[j]));
      }
    }
    __syncthreads();
    if (tid<16){
      s_feats[l*32+tid]    = s_sum[tid]/(float)cnts[l];
      s_feats[l*32+16+tid] = __uint_as_float(s_max16[tid]);
    }
    if (l==2) break;
    // ---- top-k: register-resident wave-redundant bitwise search
    {
      const int kk = kks[l];
      unsigned kreg[8];
      #pragma unroll
      for (int j=0;j<8;j++) kreg[j] = s_keys[lane + j*64];
      unsigned cur = 0u;
      for (int bit=31; bit>=0; --bit){
        unsigned cand = cur | (1u<<bit);
        int c=0;
        #pragma unroll
        for (int j=0;j<8;j++) c += __popcll(__ballot(kreg[j]>=cand));
        if (c >= kk) cur = cand;
      }
      int cgt=0;
      #pragma unroll
      for (int j=0;j<8;j++) cgt += __popcll(__ballot(kreg[j]>cur));
      int ties = kk - cgt;
      // rank among equals by node index (jax top_k lowest-index tie-break)
      unsigned myk = (tid<NPG) ? s_keys[tid] : 0u;
      bool eq = (tid<NPG) && (myk==cur);
      unsigned long long bal = __ballot(eq);
      int lrank = __popcll(bal & ((1ull<<lane)-1ull));
      if (lane==0) s_w[wv] = __popcll(bal);
      __syncthreads();
      int pre=0;
      #pragma unroll
      for (int w=0; w<16; ++w) if (w<wv) pre += s_w[w];
      int rank = pre + lrank;
      if (tid < NPG){
        bool keep = (myk > cur) || (eq && rank < ties);
        float mult = keep ? fdec(myk) : 0.f;   // exact tanh-score roundtrip
        #pragma unroll
        for (int c=0;c<8;c++){
          float2 t2 = *(const float2*)&s_z[tid*XS+2*c];
          t2.x *= mult; t2.y *= mult;
          *(float2*)&s_x[tid*XS+2*c] = t2;
        }
        s_mask[tid] = keep ? 1 : 0;
      }
    }
    __syncthreads();
    // ---- compact surviving edges (re-bin by dst) + rebuild descending perm
    {
      int ne = s_off[NPG];
      unsigned pk0=0, pk1=0; unsigned short dd0=0, dd1=0; bool k0=false,k1=false;
      if (tid < ne){
        pk0 = s_epk[tid]; dd0 = s_edst[tid];
        k0 = s_mask[pk0 & 511] && s_mask[dd0];
      }
      if (tid+1024 < ne){
        pk1 = s_epk[tid+1024]; dd1 = s_edst[tid+1024];
        k1 = s_mask[pk1 & 511] && s_mask[dd1];
      }
      __syncthreads();
      for (int i=tid;i<NPG;i+=1024) s_hist[i]=0;
      if (tid<64) s_dh[tid]=0;
      __syncthreads();
      if (k0) atomicAdd(&s_hist[dd0], 1);
      if (k1) atomicAdd(&s_hist[dd1], 1);
      __syncthreads();
      scan512(s_hist, s_off, s_wt, tid);
      __syncthreads();
      if (k0){ int p=atomicAdd(&s_hist[dd0],1); s_epk[p]=(unsigned short)pk0; s_edst[p]=dd0; }
      if (k1){ int p=atomicAdd(&s_hist[dd1],1); s_epk[p]=(unsigned short)pk1; s_edst[p]=dd1; }
      int mydeg=0, mybin=0;
      if (tid<NPG){
        mydeg = s_off[tid+1]-s_off[tid]; if (mydeg>63) mydeg=63;
        mybin = 63-mydeg;
        atomicAdd(&s_dh[mybin], 1);
      }
      __syncthreads();
      if (tid<64){
        int c = s_dh[tid], inc = c;
        #pragma unroll
        for (int o=1;o<64;o<<=1){ int t=__shfl_up(inc,o); if (tid>=o) inc+=t; }
        s_dh[tid] = inc - c;
      }
      __syncthreads();
      if (tid<NPG){ int p = atomicAdd(&s_dh[mybin],1); s_perm[p]=(unsigned short)tid; }
      __syncthreads();
    }
  }

  // ---- MLP head (feats never leave LDS)
  __syncthreads();
  if (tid < 16){
    float a = b1[tid];
    for (int i=0;i<96;i++) a += s_feats[i]*w1[i*16+tid];
    s_h1[tid] = a>0.f?a:0.f;
  }
  __syncthreads();
  if (tid < 4){
    float a = b2[tid];
    #pragma unroll
    for (int i=0;i<16;i++) a += s_h1[i]*w2[i*4+tid];
    s_h2[tid] = a>0.f?a:0.f;
  }
  __syncthreads();
  if (tid == 0){
    float z = b3[0];
    #pragma unroll
    for (int i=0;i<4;i++) z += s_h2[i]*w3[i];
    out[b] = 1.f/(1.f+expf(-z));
  }
}

extern "C" void kernel_launch(void* const* d_in, const int* in_sizes, int n_in,
                              void* d_out, int out_size, void* d_ws, size_t ws_size,
                              hipStream_t stream) {
  const float* emb    = (const float*)d_in[0];
  const float* gnn_w  = (const float*)d_in[1];
  const float* gnn_q  = (const float*)d_in[2];
  const float* gnn_k  = (const float*)d_in[3];
  const float* gnn_b  = (const float*)d_in[4];
  const float* pool_w = (const float*)d_in[5];
  const float* w1 = (const float*)d_in[6];
  const float* b1 = (const float*)d_in[7];
  const float* w2 = (const float*)d_in[8];
  const float* b2 = (const float*)d_in[9];
  const float* w3 = (const float*)d_in[10];
  const float* b3 = (const float*)d_in[11];
  const int* xattr = (const int*)d_in[12];
  const int* eidx  = (const int*)d_in[13];
  const int* etype = (const int*)d_in[14];
  const int* src = eidx;
  const int* dst = eidx + (size_t)B_*EPG;

  k_fused<<<B_, 1024, 0, stream>>>(emb, gnn_w, gnn_q, gnn_k, gnn_b, pool_w,
                                   w1, b1, w2, b2, w3, b3,
                                   xattr, src, dst, etype, (float*)d_out);
}